// Round 10
// baseline (834.529 us; speedup 1.0000x reference)
//
#include <hip/hip_runtime.h>
#include <hip/hip_bf16.h>

#define N_A 100000
#define N_B 100000
#define E_AA 400000
#define E_AB 800000
#define E_BA 800000
#define SCAN_N (2*N_A + N_B)                    // 300000 concatenated degree slots
#define SCAN_BLOCKS ((SCAN_N + 1023) / 1024)    // 293

// ---------------------------------------------------------------------------
// Layer-0 closed form (hA0/hB0 are single tiled rows):
// hA1[i] = relu(cA + deg_aa[i]*u + deg_ba[i]*v), hB1[i] = relu(cB + deg_ab[i]*w)
// sv = [cA, u_aa, v_ba, cB, w_ab]
// ---------------------------------------------------------------------------
__global__ void precompute_vecs(const float* __restrict__ emb_A, const float* __restrict__ emb_B,
    const float* __restrict__ W_aa, const float* __restrict__ b_aa,
    const float* __restrict__ W_ab, const float* __restrict__ b_ab,
    const float* __restrict__ W_ba, const float* __restrict__ b_ba,
    const float* __restrict__ Wn_A, const float* __restrict__ bn_A,
    const float* __restrict__ Wn_B, const float* __restrict__ bn_B,
    float* __restrict__ sv)
{
    __shared__ float ea[64], eb[64], maa[64], mab[64], mba[64];
    int j = threadIdx.x;
    ea[j] = emb_A[j];
    eb[j] = emb_B[j];
    __syncthreads();
    float s_aa = b_aa[j], s_ab = b_ab[j], s_ba = b_ba[j];
    for (int k = 0; k < 64; ++k) {
        s_aa += ea[k] * W_aa[k*64 + j];
        s_ab += ea[k] * W_ab[k*64 + j];
        s_ba += eb[k] * W_ba[k*64 + j];
    }
    maa[j] = fmaxf(s_aa, 0.f);
    mab[j] = fmaxf(s_ab, 0.f);
    mba[j] = fmaxf(s_ba, 0.f);
    __syncthreads();
    float cA = bn_A[j], u = 0.f, v = 0.f, cB = bn_B[j], w = 0.f;
    for (int k = 0; k < 64; ++k) {
        cA += ea[k]  * Wn_A[k*64 + j];
        u  += maa[k] * Wn_A[(64+k)*64 + j];
        v  += mba[k] * Wn_A[(128+k)*64 + j];
        cB += eb[k]  * Wn_B[k*64 + j];
        w  += mab[k] * Wn_B[(64+k)*64 + j];
    }
    sv[j] = cA; sv[64+j] = u; sv[128+j] = v; sv[192+j] = cB; sv[256+j] = w;
}

__global__ void deg_hist(const int* __restrict__ dst, int n, int* __restrict__ deg)
{
    int i = blockIdx.x * blockDim.x + threadIdx.x;
    if (i < n) atomicAdd(deg + dst[i], 1);
}

// ---------------------------------------------------------------------------
// Hierarchical exclusive scan over the 300k concatenated degree array.
// ---------------------------------------------------------------------------
__global__ __launch_bounds__(1024) void scan_blocks(const int* __restrict__ deg,
                                                    int* __restrict__ scan_tmp,
                                                    int* __restrict__ partials)
{
    __shared__ int ps[1024];
    int tid = threadIdx.x;
    int gid = blockIdx.x * 1024 + tid;
    int v = (gid < SCAN_N) ? deg[gid] : 0;
    ps[tid] = v;
    __syncthreads();
    for (int off = 1; off < 1024; off <<= 1) {
        int t = (tid >= off) ? ps[tid - off] : 0;
        __syncthreads();
        ps[tid] += t;
        __syncthreads();
    }
    if (gid < SCAN_N) scan_tmp[gid] = ps[tid] - v;   // local exclusive
    if (tid == 1023) partials[blockIdx.x] = ps[1023];
}

__global__ __launch_bounds__(512) void scan_partials(int* __restrict__ partials)
{
    __shared__ int ps[512];
    int tid = threadIdx.x;
    int v = (tid < SCAN_BLOCKS) ? partials[tid] : 0;
    ps[tid] = v;
    __syncthreads();
    for (int off = 1; off < 512; off <<= 1) {
        int t = (tid >= off) ? ps[tid - off] : 0;
        __syncthreads();
        ps[tid] += t;
        __syncthreads();
    }
    partials[tid] = ps[tid] - v;                     // exclusive
    if (tid == 511) partials[512] = ps[511];         // grand total
}

__global__ __launch_bounds__(1024) void scan_finalize(const int* __restrict__ scan_tmp,
                                                      const int* __restrict__ partials,
                                                      int* __restrict__ rp,
                                                      int* __restrict__ cur)
{
    int gid = blockIdx.x * 1024 + threadIdx.x;
    if (gid < SCAN_N) {
        int v = scan_tmp[gid] + partials[blockIdx.x];
        rp[gid] = v;
        cur[gid] = v;
    }
    if (gid == 0) rp[SCAN_N] = partials[512];
}

// counting-sort fill: perm[] = src indices grouped by dst (global positions)
__global__ void fill_perm(const int* __restrict__ src, const int* __restrict__ dst, int ne,
                          int* __restrict__ cur, int* __restrict__ perm)
{
    int i = blockIdx.x * blockDim.x + threadIdx.x;
    if (i < ne) {
        int p = atomicAdd(cur + dst[i], 1);
        perm[p] = src[i];
    }
}

__global__ void layer0_nodes(const int* __restrict__ deg_aa, const int* __restrict__ deg_ba,
                             const int* __restrict__ deg_ab, const float* __restrict__ sv,
                             float* __restrict__ hA1, float* __restrict__ hB1)
{
    __shared__ float s[320];
    for (int t = threadIdx.x; t < 320; t += blockDim.x)
        s[t] = sv[t];
    __syncthreads();
    int gid = blockIdx.x * blockDim.x + threadIdx.x;
    int total = (N_A + N_B) * 64;
    for (int idx = gid; idx < total; idx += gridDim.x * blockDim.x) {
        int i = idx >> 6, j = idx & 63;
        if (i < N_A) {
            float da = (float)deg_aa[i];
            float db = (float)deg_ba[i];
            hA1[idx] = fmaxf(s[j] + da * s[64+j] + db * s[128+j], 0.f);
        } else {
            int b = i - N_A;
            float dd = (float)deg_ab[b];
            hB1[(size_t)b*64 + j] = fmaxf(s[192+j] + dd * s[256+j], 0.f);
        }
    }
}

// ---------------------------------------------------------------------------
// g = relu(h @ W + b). Block = 256 threads, 16 rows, thread = 4 cols of a row.
// Weights read straight from global (L1/L2-broadcast across blocks).
// ---------------------------------------------------------------------------
__global__ __launch_bounds__(256) void node_transform(
    const float* __restrict__ h,
    const float* __restrict__ W0, const float* __restrict__ b0,
    float* __restrict__ g0)
{
    __shared__ float hs[16][65];
    int tid = threadIdx.x;
    size_t rbase = (size_t)blockIdx.x * 16;
    for (int t = tid; t < 1024; t += 256)
        hs[t >> 6][t & 63] = h[rbase * 64 + t];
    __syncthreads();
    int r  = tid >> 4;
    int c0 = (tid & 15) * 4;
    float a0 = b0[c0], a1 = b0[c0+1], a2 = b0[c0+2], a3 = b0[c0+3];
    #pragma unroll 8
    for (int k = 0; k < 64; ++k) {
        float hv = hs[r][k];
        float4 w0 = *(const float4*)&W0[k*64 + c0];
        a0 += hv*w0.x; a1 += hv*w0.y; a2 += hv*w0.z; a3 += hv*w0.w;
    }
    size_t o = (rbase + r) * 64 + c0;
    *(float4*)(g0 + o) = make_float4(fmaxf(a0,0.f), fmaxf(a1,0.f), fmaxf(a2,0.f), fmaxf(a3,0.f));
}

// ---------------------------------------------------------------------------
// Standalone CSR gather: r[node] = sum over nbrs of g[src]. LDS-free, low
// VGPR -> max occupancy; 16 lanes/node, float4/lane, 4-wide MLP unroll.
// ---------------------------------------------------------------------------
__global__ __launch_bounds__(256) void gather_csr(
    const int* __restrict__ rp, const int* __restrict__ pm,
    const float* __restrict__ g, float* __restrict__ r, int n)
{
    int gid = blockIdx.x * 256 + threadIdx.x;
    int node = gid >> 4;
    int l = gid & 15;
    if (node >= n) return;
    int e0 = rp[node], e1 = rp[node + 1];
    float4 A = make_float4(0.f,0.f,0.f,0.f), B = make_float4(0.f,0.f,0.f,0.f);
    float4 C = make_float4(0.f,0.f,0.f,0.f), D = make_float4(0.f,0.f,0.f,0.f);
    int e = e0;
    for (; e + 3 < e1; e += 4) {
        int s0 = pm[e], s1 = pm[e+1], s2 = pm[e+2], s3 = pm[e+3];
        float4 v0 = *(const float4*)(g + (size_t)s0 * 64 + l * 4);
        float4 v1 = *(const float4*)(g + (size_t)s1 * 64 + l * 4);
        float4 v2 = *(const float4*)(g + (size_t)s2 * 64 + l * 4);
        float4 v3 = *(const float4*)(g + (size_t)s3 * 64 + l * 4);
        A.x += v0.x; A.y += v0.y; A.z += v0.z; A.w += v0.w;
        B.x += v1.x; B.y += v1.y; B.z += v1.z; B.w += v1.w;
        C.x += v2.x; C.y += v2.y; C.z += v2.z; C.w += v2.w;
        D.x += v3.x; D.y += v3.y; D.z += v3.z; D.w += v3.w;
    }
    for (; e < e1; ++e) {
        float4 v = *(const float4*)(g + (size_t)pm[e] * 64 + l * 4);
        A.x += v.x; A.y += v.y; A.z += v.z; A.w += v.w;
    }
    *(float4*)(r + (size_t)node * 64 + l * 4) =
        make_float4(A.x+B.x+C.x+D.x, A.y+B.y+C.y+D.y,
                    A.z+B.z+C.z+D.z, A.w+B.w+C.w+D.w);
}

// ---------------------------------------------------------------------------
// out = relu(concat(h, r0, [r1]) @ Wn + bn). r0/r1 may alias out (each block
// reads only its own 16 rows into LDS before writing them back).
// Weights read from global (no LDS stage) -> LDS 12.5/8.4 KB -> ~4 blocks/CU.
// ---------------------------------------------------------------------------
template<int NS>
__global__ __launch_bounds__(256) void node_update(
    const float* __restrict__ h,
    const float* r0,                  // no restrict: may alias out
    const float* r1,                  // no restrict: may alias out
    const float* __restrict__ Wn, const float* __restrict__ bn,
    float* out)
{
    __shared__ float hs[NS][16][65];
    int tid = threadIdx.x;
    size_t rbase = (size_t)blockIdx.x * 16;
    for (int t = tid; t < 1024; t += 256) {
        int rr = t >> 6, k = t & 63;
        size_t gi = rbase * 64 + t;
        hs[0][rr][k] = h[gi];
        hs[1][rr][k] = r0[gi];
        if constexpr (NS == 3) hs[2][rr][k] = r1[gi];
    }
    __syncthreads();
    int r  = tid >> 4;
    int c0 = (tid & 15) * 4;
    float a0 = bn[c0], a1 = bn[c0+1], a2 = bn[c0+2], a3 = bn[c0+3];
    for (int s = 0; s < NS; ++s) {
        #pragma unroll 8
        for (int k = 0; k < 64; ++k) {
            float hv = hs[s][r][k];
            float4 w = *(const float4*)&Wn[(s*64 + k)*64 + c0];
            a0 += hv*w.x; a1 += hv*w.y; a2 += hv*w.z; a3 += hv*w.w;
        }
    }
    *(float4*)(out + (rbase + r) * 64 + c0) =
        make_float4(fmaxf(a0,0.f), fmaxf(a1,0.f), fmaxf(a2,0.f), fmaxf(a3,0.f));
}

extern "C" void kernel_launch(void* const* d_in, const int* in_sizes, int n_in,
                              void* d_out, int out_size, void* d_ws, size_t ws_size,
                              hipStream_t stream)
{
    const int*   src_aa = (const int*)d_in[0];
    const int*   dst_aa = (const int*)d_in[1];
    const int*   src_ab = (const int*)d_in[2];
    const int*   dst_ab = (const int*)d_in[3];
    const int*   src_ba = (const int*)d_in[4];
    const int*   dst_ba = (const int*)d_in[5];
    const float* emb_A  = (const float*)d_in[6];
    const float* emb_B  = (const float*)d_in[7];
    const float* W_aa   = (const float*)d_in[8];
    const float* b_aa   = (const float*)d_in[9];
    const float* W_ab   = (const float*)d_in[10];
    const float* b_ab   = (const float*)d_in[11];
    const float* W_ba   = (const float*)d_in[12];
    const float* b_ba   = (const float*)d_in[13];
    const float* Wn_A   = (const float*)d_in[14];
    const float* bn_A   = (const float*)d_in[15];
    const float* Wn_B   = (const float*)d_in[16];
    const float* bn_B   = (const float*)d_in[17];

    // workspace (~116 MiB):
    // sv[512] | deg_all[300k] | scan_tmp[300k] | rp_all[300k+1] | cur_all[300k]
    // | partials[640] | perm_all[2M] | hA1 | hB1 | gX | gY
    // r-buffer overlays: r_aa -> outA, r_ba -> outB, r_ab -> gY (after free).
    float* ws   = (float*)d_ws;
    float* sv   = ws;
    int*   ib   = (int*)(ws + 512);
    int* deg_all  = ib;                 ib += SCAN_N;
    int* scan_tmp = ib;                 ib += SCAN_N;
    int* rp_all   = ib;                 ib += SCAN_N + 1;
    int* cur_all  = ib;                 ib += SCAN_N;
    int* partials = ib;                 ib += 640;
    int* perm_all = ib;                 ib += E_AA + E_BA + E_AB;
    float* hA1 = (float*)ib;
    float* hB1 = hA1 + (size_t)N_A * 64;
    float* gX  = hB1 + (size_t)N_B * 64;   // g_aa, then reused as g_ab
    float* gY  = gX  + (size_t)N_A * 64;   // g_ba, then reused as r_ab

    float* outA = (float*)d_out;           // doubles as r_aa
    float* outB = outA + (size_t)N_A * 64; // doubles as r_ba (until update B)

    hipMemsetAsync(deg_all, 0, (size_t)SCAN_N * sizeof(int), stream);

    precompute_vecs<<<1, 64, 0, stream>>>(emb_A, emb_B, W_aa, b_aa, W_ab, b_ab,
                                          W_ba, b_ba, Wn_A, bn_A, Wn_B, bn_B, sv);
    deg_hist<<<(E_AA + 255) / 256, 256, 0, stream>>>(dst_aa, E_AA, deg_all);            // aa
    deg_hist<<<(E_BA + 255) / 256, 256, 0, stream>>>(dst_ba, E_BA, deg_all + N_A);      // ba
    deg_hist<<<(E_AB + 255) / 256, 256, 0, stream>>>(dst_ab, E_AB, deg_all + 2*N_A);    // ab

    scan_blocks  <<<SCAN_BLOCKS, 1024, 0, stream>>>(deg_all, scan_tmp, partials);
    scan_partials<<<1, 512, 0, stream>>>(partials);
    scan_finalize<<<SCAN_BLOCKS, 1024, 0, stream>>>(scan_tmp, partials, rp_all, cur_all);

    layer0_nodes<<<4096, 256, 0, stream>>>(deg_all, deg_all + N_A, deg_all + 2*N_A,
                                           sv, hA1, hB1);

    fill_perm<<<(E_AA + 255) / 256, 256, 0, stream>>>(src_aa, dst_aa, E_AA, cur_all,         perm_all);
    fill_perm<<<(E_BA + 255) / 256, 256, 0, stream>>>(src_ba, dst_ba, E_BA, cur_all + N_A,   perm_all);
    fill_perm<<<(E_AB + 255) / 256, 256, 0, stream>>>(src_ab, dst_ab, E_AB, cur_all + 2*N_A, perm_all);

    // layer-1 per-node edge transforms (layer-1 weight offsets)
    node_transform<<<N_A / 16, 256, 0, stream>>>(hA1, W_aa + 4096, b_aa + 64, gX);  // g_aa
    node_transform<<<N_B / 16, 256, 0, stream>>>(hB1, W_ba + 4096, b_ba + 64, gY);  // g_ba

    // atomic-free CSR gathers (LDS-free, max occupancy)
    gather_csr<<<(N_A * 16) / 256, 256, 0, stream>>>(rp_all,         perm_all, gX, outA, N_A); // r_aa
    gather_csr<<<(N_A * 16) / 256, 256, 0, stream>>>(rp_all + N_A,   perm_all, gY, outB, N_A); // r_ba

    // A update: concat [hA1, r_aa(outA), r_ba(outB)] -> outA
    node_update<3><<<N_A / 16, 256, 0, stream>>>(hA1, outA, outB,
                                                 Wn_A + 12288, bn_A + 64, outA);

    // gX dead -> g_ab; gY dead -> r_ab
    node_transform<<<N_A / 16, 256, 0, stream>>>(hA1, W_ab + 4096, b_ab + 64, gX);
    gather_csr<<<(N_B * 16) / 256, 256, 0, stream>>>(rp_all + 2*N_A, perm_all, gX, gY, N_B);   // r_ab

    // B update: concat [hB1, r_ab(gY)] -> outB
    node_update<2><<<N_B / 16, 256, 0, stream>>>(hB1, gY, nullptr,
                                                 Wn_B + 8192, bn_B + 64, outB);
}

// Round 11
// 584.519 us; speedup vs baseline: 1.4277x; 1.4277x over previous
//
#include <hip/hip_runtime.h>
#include <hip/hip_bf16.h>

#define N_A 100000
#define N_B 100000
#define E_AA 400000
#define E_AB 800000
#define E_BA 800000
#define SCAN_N (2*N_A + N_B)                    // 300000 concatenated degree slots
#define SCAN_BLOCKS ((SCAN_N + 1023) / 1024)    // 293

__device__ __forceinline__ void fma4(float4& a, float s, const float4 w) {
    a.x += s*w.x; a.y += s*w.y; a.z += s*w.z; a.w += s*w.w;
}

// ---------------------------------------------------------------------------
// Layer-0 closed form: sv = [cA, u_aa, v_ba, cB, w_ab]
// ---------------------------------------------------------------------------
__global__ void precompute_vecs(const float* __restrict__ emb_A, const float* __restrict__ emb_B,
    const float* __restrict__ W_aa, const float* __restrict__ b_aa,
    const float* __restrict__ W_ab, const float* __restrict__ b_ab,
    const float* __restrict__ W_ba, const float* __restrict__ b_ba,
    const float* __restrict__ Wn_A, const float* __restrict__ bn_A,
    const float* __restrict__ Wn_B, const float* __restrict__ bn_B,
    float* __restrict__ sv)
{
    __shared__ float ea[64], eb[64], maa[64], mab[64], mba[64];
    int j = threadIdx.x;
    ea[j] = emb_A[j];
    eb[j] = emb_B[j];
    __syncthreads();
    float s_aa = b_aa[j], s_ab = b_ab[j], s_ba = b_ba[j];
    for (int k = 0; k < 64; ++k) {
        s_aa += ea[k] * W_aa[k*64 + j];
        s_ab += ea[k] * W_ab[k*64 + j];
        s_ba += eb[k] * W_ba[k*64 + j];
    }
    maa[j] = fmaxf(s_aa, 0.f);
    mab[j] = fmaxf(s_ab, 0.f);
    mba[j] = fmaxf(s_ba, 0.f);
    __syncthreads();
    float cA = bn_A[j], u = 0.f, v = 0.f, cB = bn_B[j], w = 0.f;
    for (int k = 0; k < 64; ++k) {
        cA += ea[k]  * Wn_A[k*64 + j];
        u  += maa[k] * Wn_A[(64+k)*64 + j];
        v  += mba[k] * Wn_A[(128+k)*64 + j];
        cB += eb[k]  * Wn_B[k*64 + j];
        w  += mab[k] * Wn_B[(64+k)*64 + j];
    }
    sv[j] = cA; sv[64+j] = u; sv[128+j] = v; sv[192+j] = cB; sv[256+j] = w;
}

__global__ void deg_hist(const int* __restrict__ dst, int n, int* __restrict__ deg)
{
    int i = blockIdx.x * blockDim.x + threadIdx.x;
    if (i < n) atomicAdd(deg + dst[i], 1);
}

// ---------------------------------------------------------------------------
// Hierarchical exclusive scan over the 300k concatenated degree array.
// ---------------------------------------------------------------------------
__global__ __launch_bounds__(1024) void scan_blocks(const int* __restrict__ deg,
                                                    int* __restrict__ scan_tmp,
                                                    int* __restrict__ partials)
{
    __shared__ int ps[1024];
    int tid = threadIdx.x;
    int gid = blockIdx.x * 1024 + tid;
    int v = (gid < SCAN_N) ? deg[gid] : 0;
    ps[tid] = v;
    __syncthreads();
    for (int off = 1; off < 1024; off <<= 1) {
        int t = (tid >= off) ? ps[tid - off] : 0;
        __syncthreads();
        ps[tid] += t;
        __syncthreads();
    }
    if (gid < SCAN_N) scan_tmp[gid] = ps[tid] - v;   // local exclusive
    if (tid == 1023) partials[blockIdx.x] = ps[1023];
}

__global__ __launch_bounds__(512) void scan_partials(int* __restrict__ partials)
{
    __shared__ int ps[512];
    int tid = threadIdx.x;
    int v = (tid < SCAN_BLOCKS) ? partials[tid] : 0;
    ps[tid] = v;
    __syncthreads();
    for (int off = 1; off < 512; off <<= 1) {
        int t = (tid >= off) ? ps[tid - off] : 0;
        __syncthreads();
        ps[tid] += t;
        __syncthreads();
    }
    partials[tid] = ps[tid] - v;                     // exclusive
    if (tid == 511) partials[512] = ps[511];         // grand total
}

__global__ __launch_bounds__(1024) void scan_finalize(const int* __restrict__ scan_tmp,
                                                      const int* __restrict__ partials,
                                                      int* __restrict__ rp,
                                                      int* __restrict__ cur)
{
    int gid = blockIdx.x * 1024 + threadIdx.x;
    if (gid < SCAN_N) {
        int v = scan_tmp[gid] + partials[blockIdx.x];
        rp[gid] = v;
        cur[gid] = v;
    }
    if (gid == 0) rp[SCAN_N] = partials[512];
}

// counting-sort fill: perm[] = src indices grouped by dst (global positions)
__global__ void fill_perm(const int* __restrict__ src, const int* __restrict__ dst, int ne,
                          int* __restrict__ cur, int* __restrict__ perm)
{
    int i = blockIdx.x * blockDim.x + threadIdx.x;
    if (i < ne) {
        int p = atomicAdd(cur + dst[i], 1);
        perm[p] = src[i];
    }
}

__global__ void layer0_nodes(const int* __restrict__ deg_aa, const int* __restrict__ deg_ba,
                             const int* __restrict__ deg_ab, const float* __restrict__ sv,
                             float* __restrict__ hA1, float* __restrict__ hB1)
{
    __shared__ float s[320];
    for (int t = threadIdx.x; t < 320; t += blockDim.x)
        s[t] = sv[t];
    __syncthreads();
    int gid = blockIdx.x * blockDim.x + threadIdx.x;
    int total = (N_A + N_B) * 64;
    for (int idx = gid; idx < total; idx += gridDim.x * blockDim.x) {
        int i = idx >> 6, j = idx & 63;
        if (i < N_A) {
            float da = (float)deg_aa[i];
            float db = (float)deg_ba[i];
            hA1[idx] = fmaxf(s[j] + da * s[64+j] + db * s[128+j], 0.f);
        } else {
            int b = i - N_A;
            float dd = (float)deg_ab[b];
            hB1[(size_t)b*64 + j] = fmaxf(s[192+j] + dd * s[256+j], 0.f);
        }
    }
}

// ---------------------------------------------------------------------------
// Unified GEMM: out = relu(concat(srcs[0..NS-1]) @ Wn + bn), K = NS*64.
// W staged in LDS (reused by all rows); h/r rows read as per-thread global
// float4 (L1 broadcast within 16-lane group) -> LDS pipe carries only W.
// Block = 256 thr, 32 rows (group g owns rows 2g,2g+1), grid = N/32 = 3125.
// r0/r1 may alias out: each thread reads only its own 2 rows, writes them last.
// ---------------------------------------------------------------------------
template<int NS>
__global__ __launch_bounds__(256) void node_update(
    const float* __restrict__ h,
    const float* r0,                  // no restrict: may alias out
    const float* r1,                  // no restrict: may alias out
    const float* __restrict__ Wn, const float* __restrict__ bn,
    float* out)
{
    __shared__ float Ws[NS * 4096];
    int tid = threadIdx.x;
    for (int t = tid; t < NS * 4096; t += 256) Ws[t] = Wn[t];
    __syncthreads();
    int g  = tid >> 4;
    int c0 = (tid & 15) * 4;
    size_t row0 = (size_t)blockIdx.x * 32 + g * 2;
    float4 acc0 = make_float4(bn[c0], bn[c0+1], bn[c0+2], bn[c0+3]);
    float4 acc1 = acc0;
    const float* srcs[3] = {h, r0, r1};
    #pragma unroll
    for (int s = 0; s < NS; ++s) {
        const float* p0 = srcs[s] + row0 * 64;
        const float* p1 = p0 + 64;
        #pragma unroll
        for (int k4 = 0; k4 < 16; ++k4) {
            float4 h0 = *(const float4*)(p0 + k4 * 4);
            float4 h1 = *(const float4*)(p1 + k4 * 4);
            const float* wb = &Ws[s*4096 + k4*256 + c0];
            float4 w0 = *(const float4*)(wb);
            float4 w1 = *(const float4*)(wb + 64);
            float4 w2 = *(const float4*)(wb + 128);
            float4 w3 = *(const float4*)(wb + 192);
            fma4(acc0, h0.x, w0); fma4(acc0, h0.y, w1);
            fma4(acc0, h0.z, w2); fma4(acc0, h0.w, w3);
            fma4(acc1, h1.x, w0); fma4(acc1, h1.y, w1);
            fma4(acc1, h1.z, w2); fma4(acc1, h1.w, w3);
        }
    }
    *(float4*)(out + row0 * 64 + c0) =
        make_float4(fmaxf(acc0.x,0.f), fmaxf(acc0.y,0.f), fmaxf(acc0.z,0.f), fmaxf(acc0.w,0.f));
    *(float4*)(out + row0 * 64 + 64 + c0) =
        make_float4(fmaxf(acc1.x,0.f), fmaxf(acc1.y,0.f), fmaxf(acc1.z,0.f), fmaxf(acc1.w,0.f));
}

// ---------------------------------------------------------------------------
// Standalone CSR gather: r[node] = sum over nbrs of g[src]. LDS-free, low
// VGPR -> max occupancy; 16 lanes/node, float4/lane, 4-wide MLP unroll.
// ---------------------------------------------------------------------------
__global__ __launch_bounds__(256) void gather_csr(
    const int* __restrict__ rp, const int* __restrict__ pm,
    const float* __restrict__ g, float* __restrict__ r, int n)
{
    int gid = blockIdx.x * 256 + threadIdx.x;
    int node = gid >> 4;
    int l = gid & 15;
    if (node >= n) return;
    int e0 = rp[node], e1 = rp[node + 1];
    float4 A = make_float4(0.f,0.f,0.f,0.f), B = make_float4(0.f,0.f,0.f,0.f);
    float4 C = make_float4(0.f,0.f,0.f,0.f), D = make_float4(0.f,0.f,0.f,0.f);
    int e = e0;
    for (; e + 3 < e1; e += 4) {
        int s0 = pm[e], s1 = pm[e+1], s2 = pm[e+2], s3 = pm[e+3];
        float4 v0 = *(const float4*)(g + (size_t)s0 * 64 + l * 4);
        float4 v1 = *(const float4*)(g + (size_t)s1 * 64 + l * 4);
        float4 v2 = *(const float4*)(g + (size_t)s2 * 64 + l * 4);
        float4 v3 = *(const float4*)(g + (size_t)s3 * 64 + l * 4);
        A.x += v0.x; A.y += v0.y; A.z += v0.z; A.w += v0.w;
        B.x += v1.x; B.y += v1.y; B.z += v1.z; B.w += v1.w;
        C.x += v2.x; C.y += v2.y; C.z += v2.z; C.w += v2.w;
        D.x += v3.x; D.y += v3.y; D.z += v3.z; D.w += v3.w;
    }
    for (; e < e1; ++e) {
        float4 v = *(const float4*)(g + (size_t)pm[e] * 64 + l * 4);
        A.x += v.x; A.y += v.y; A.z += v.z; A.w += v.w;
    }
    *(float4*)(r + (size_t)node * 64 + l * 4) =
        make_float4(A.x+B.x+C.x+D.x, A.y+B.y+C.y+D.y,
                    A.z+B.z+C.z+D.z, A.w+B.w+C.w+D.w);
}

extern "C" void kernel_launch(void* const* d_in, const int* in_sizes, int n_in,
                              void* d_out, int out_size, void* d_ws, size_t ws_size,
                              hipStream_t stream)
{
    const int*   src_aa = (const int*)d_in[0];
    const int*   dst_aa = (const int*)d_in[1];
    const int*   src_ab = (const int*)d_in[2];
    const int*   dst_ab = (const int*)d_in[3];
    const int*   src_ba = (const int*)d_in[4];
    const int*   dst_ba = (const int*)d_in[5];
    const float* emb_A  = (const float*)d_in[6];
    const float* emb_B  = (const float*)d_in[7];
    const float* W_aa   = (const float*)d_in[8];
    const float* b_aa   = (const float*)d_in[9];
    const float* W_ab   = (const float*)d_in[10];
    const float* b_ab   = (const float*)d_in[11];
    const float* W_ba   = (const float*)d_in[12];
    const float* b_ba   = (const float*)d_in[13];
    const float* Wn_A   = (const float*)d_in[14];
    const float* bn_A   = (const float*)d_in[15];
    const float* Wn_B   = (const float*)d_in[16];
    const float* bn_B   = (const float*)d_in[17];

    // workspace (~116 MiB):
    // sv[512] | deg_all[300k] | scan_tmp[300k] | rp_all[300k+1] | cur_all[300k]
    // | partials[640] | perm_all[2M] | hA1 | hB1 | gX | gY
    // r-buffer overlays: r_aa -> outA, r_ba -> outB, r_ab -> gY (after free).
    float* ws   = (float*)d_ws;
    float* sv   = ws;
    int*   ib   = (int*)(ws + 512);
    int* deg_all  = ib;                 ib += SCAN_N;
    int* scan_tmp = ib;                 ib += SCAN_N;
    int* rp_all   = ib;                 ib += SCAN_N + 1;
    int* cur_all  = ib;                 ib += SCAN_N;
    int* partials = ib;                 ib += 640;
    int* perm_all = ib;                 ib += E_AA + E_BA + E_AB;
    float* hA1 = (float*)ib;
    float* hB1 = hA1 + (size_t)N_A * 64;
    float* gX  = hB1 + (size_t)N_B * 64;   // g_aa, then reused as g_ab
    float* gY  = gX  + (size_t)N_A * 64;   // g_ba, then reused as r_ab

    float* outA = (float*)d_out;           // doubles as r_aa
    float* outB = outA + (size_t)N_A * 64; // doubles as r_ba (until update B)

    hipMemsetAsync(deg_all, 0, (size_t)SCAN_N * sizeof(int), stream);

    precompute_vecs<<<1, 64, 0, stream>>>(emb_A, emb_B, W_aa, b_aa, W_ab, b_ab,
                                          W_ba, b_ba, Wn_A, bn_A, Wn_B, bn_B, sv);
    deg_hist<<<(E_AA + 255) / 256, 256, 0, stream>>>(dst_aa, E_AA, deg_all);            // aa
    deg_hist<<<(E_BA + 255) / 256, 256, 0, stream>>>(dst_ba, E_BA, deg_all + N_A);      // ba
    deg_hist<<<(E_AB + 255) / 256, 256, 0, stream>>>(dst_ab, E_AB, deg_all + 2*N_A);    // ab

    scan_blocks  <<<SCAN_BLOCKS, 1024, 0, stream>>>(deg_all, scan_tmp, partials);
    scan_partials<<<1, 512, 0, stream>>>(partials);
    scan_finalize<<<SCAN_BLOCKS, 1024, 0, stream>>>(scan_tmp, partials, rp_all, cur_all);

    layer0_nodes<<<4096, 256, 0, stream>>>(deg_all, deg_all + N_A, deg_all + 2*N_A,
                                           sv, hA1, hB1);

    fill_perm<<<(E_AA + 255) / 256, 256, 0, stream>>>(src_aa, dst_aa, E_AA, cur_all,         perm_all);
    fill_perm<<<(E_BA + 255) / 256, 256, 0, stream>>>(src_ba, dst_ba, E_BA, cur_all + N_A,   perm_all);
    fill_perm<<<(E_AB + 255) / 256, 256, 0, stream>>>(src_ab, dst_ab, E_AB, cur_all + 2*N_A, perm_all);

    // layer-1 per-node edge transforms = node_update<1> (layer-1 weight offsets)
    node_update<1><<<N_A / 32, 256, 0, stream>>>(hA1, nullptr, nullptr,
                                                 W_aa + 4096, b_aa + 64, gX);   // g_aa
    node_update<1><<<N_B / 32, 256, 0, stream>>>(hB1, nullptr, nullptr,
                                                 W_ba + 4096, b_ba + 64, gY);   // g_ba

    // atomic-free CSR gathers (LDS-free, max occupancy)
    gather_csr<<<(N_A * 16) / 256, 256, 0, stream>>>(rp_all,         perm_all, gX, outA, N_A); // r_aa
    gather_csr<<<(N_A * 16) / 256, 256, 0, stream>>>(rp_all + N_A,   perm_all, gY, outB, N_A); // r_ba

    // A update: concat [hA1, r_aa(outA), r_ba(outB)] -> outA
    node_update<3><<<N_A / 32, 256, 0, stream>>>(hA1, outA, outB,
                                                 Wn_A + 12288, bn_A + 64, outA);

    // gX dead -> g_ab; gY dead -> r_ab
    node_update<1><<<N_A / 32, 256, 0, stream>>>(hA1, nullptr, nullptr,
                                                 W_ab + 4096, b_ab + 64, gX);   // g_ab
    gather_csr<<<(N_B * 16) / 256, 256, 0, stream>>>(rp_all + 2*N_A, perm_all, gX, gY, N_B);   // r_ab

    // B update: concat [hB1, r_ab(gY)] -> outB
    node_update<2><<<N_B / 32, 256, 0, stream>>>(hB1, gY, nullptr,
                                                 Wn_B + 8192, bn_B + 64, outB);
}